// Round 4
// baseline (356.346 us; speedup 1.0000x reference)
//
#include <hip/hip_runtime.h>
#include <hip/hip_bf16.h>
#include <hip/hip_fp16.h>

typedef _Float16 f16;
typedef _Float16 f16x8 __attribute__((ext_vector_type(8)));
typedef _Float16 f16x4 __attribute__((ext_vector_type(4)));
typedef _Float16 f16x2 __attribute__((ext_vector_type(2)));
typedef float f32x4 __attribute__((ext_vector_type(4)));

#define D_MODEL 768
#define S_CTX   4096
#define NBATCH  2
#define M_TOK   (NBATCH * S_CTX)   // 8192
#define N3      (3 * D_MODEL)      // 2304

// ---------------------------------------------------------------- utilities
__device__ __forceinline__ void gload_lds16(const void* g, void* l) {
  __builtin_amdgcn_global_load_lds(
      (__attribute__((address_space(1))) unsigned int*)g,
      (__attribute__((address_space(3))) unsigned int*)l, 16, 0, 0);
}

// ---------------------------------------------------------------- fp32->fp16
__global__ __launch_bounds__(256) void cvt_f32_f16(const float* __restrict__ s,
                                                   f16* __restrict__ d, int n4) {
  int i = blockIdx.x * 256 + threadIdx.x;
  if (i >= n4) return;
  f32x4 v = ((const f32x4*)s)[i];
  f16x4 h;
  h[0] = (f16)v[0]; h[1] = (f16)v[1]; h[2] = (f16)v[2]; h[3] = (f16)v[3];
  ((f16x4*)d)[i] = h;
}

// ---------------------------------------------------------------- projection
__global__ __launch_bounds__(256, 2) void proj_gemm(
    const f16* __restrict__ A, const f16* __restrict__ B,
    f16* __restrict__ qh, f16* __restrict__ kh, f16* __restrict__ vth) {
  __shared__ f16 As[128 * 32];
  __shared__ f16 Bs[128 * 32];

  const int tid  = threadIdx.x;
  const int w    = tid >> 6, lane = tid & 63;
  const int wr   = w >> 1,   wc   = w & 1;
  const int bm0  = blockIdx.x * 128, bn0 = blockIdx.y * 128;
  const int srow = lane >> 2;
  const int scol = (lane & 3) * 8;

  f32x4 acc[4][4] = {};

  const f16* gA = A + (size_t)bm0 * 768;
  const f16* gB = B + (size_t)bn0 * 768;

  for (int kt = 0; kt < 24; ++kt) {
    __syncthreads();
    const int k0 = kt * 32 + scol;
#pragma unroll
    for (int cc = 0; cc < 2; ++cc) {
      int c = w + cc * 4;
      gload_lds16(gA + (size_t)(c * 16 + srow) * 768 + k0, (char*)As + c * 1024);
      gload_lds16(gB + (size_t)(c * 16 + srow) * 768 + k0, (char*)Bs + c * 1024);
    }
    __syncthreads();

    const int fr = lane & 15, fk = (lane >> 4) * 8;
    f16x8 af[4], bf[4];
#pragma unroll
    for (int i = 0; i < 4; ++i)
      af[i] = *(const f16x8*)(As + (wr * 64 + i * 16 + fr) * 32 + fk);
#pragma unroll
    for (int j = 0; j < 4; ++j)
      bf[j] = *(const f16x8*)(Bs + (wc * 64 + j * 16 + fr) * 32 + fk);
#pragma unroll
    for (int i = 0; i < 4; ++i)
#pragma unroll
      for (int j = 0; j < 4; ++j)
        acc[i][j] = __builtin_amdgcn_mfma_f32_16x16x32_f16(af[i], bf[j], acc[i][j], 0, 0, 0);
  }

  const int fr = lane & 15, fq = lane >> 4;
#pragma unroll
  for (int i = 0; i < 4; ++i) {
#pragma unroll
    for (int j = 0; j < 4; ++j) {
      int gn      = bn0 + wc * 64 + j * 16 + fr;
      int gm_base = bm0 + wr * 64 + i * 16 + fq * 4;
      if (gn < 1536) {
        f16* dst = (gn < 768) ? qh : kh;
        int  col = (gn < 768) ? gn : gn - 768;
#pragma unroll
        for (int r = 0; r < 4; ++r)
          dst[(size_t)(gm_base + r) * 768 + col] = (f16)acc[i][j][r];
      } else {
        int d = gn - 1536;
        int bb = gm_base >> 12, s = gm_base & 4095;
        f16x4 h;
        h[0] = (f16)acc[i][j][0]; h[1] = (f16)acc[i][j][1];
        h[2] = (f16)acc[i][j][2]; h[3] = (f16)acc[i][j][3];
        *(f16x4*)(vth + ((size_t)bb * 768 + d) * 4096 + s) = h;
      }
    }
  }
}

// ---------------------------------------------------------------- attention
// 512 thr (8 waves), 1 WG/CU, KVSTEP=32. Two-stage software pipeline:
//   region A: softmax(t) || QK^T(t+1) || issue K[t+2]->LDS, V(t+1)->regs
//   region B: rescale + PV(t) with counted vmcnt (drain V(t) only)
// K double-buffered in LDS; S double-buffered; V in register double-buffer.
#define SM_K0   0
#define SM_K1   49152
#define SM_SS   98304    // float [2 parity][2 dh][32][32]
#define SM_PS   114688   // f16 [32][64B] swizzled
#define SM_M    116736
#define SM_L    116864
#define SM_F    116992
#define SM_SZ   117120

__global__ __launch_bounds__(512, 2) void attn_part(
    const f16* __restrict__ qg, const f16* __restrict__ kg,
    const f16* __restrict__ vt, f16* __restrict__ p0,
    float* __restrict__ p1, float* __restrict__ ml) {
  extern __shared__ __align__(16) char smem[];
  char*  Ps = smem + SM_PS;
  float* mS = (float*)(smem + SM_M);
  float* lS = (float*)(smem + SM_L);
  float* fS = (float*)(smem + SM_F);

  const int tid  = threadIdx.x;
  const int wv   = tid >> 6, lane = tid & 63;
  const int fr   = lane & 15, fq = lane >> 4;
  const int qi   = wv >> 2, ki = (wv >> 1) & 1, dh = wv & 1;

  // pairing schedule (as R3): round 1 qb 127..64 desc, round 2 qb 63..0 desc
  const int u = blockIdx.x;
  int vv = (u < 256) ? u : (u - 256);
  const int qb = ((u < 256) ? 127 : 63) - (vv >> 2);
  const int b  = (vv >> 1) & 1;
  const int c  = vv & 1;
  const int q0 = qb * 32;
  const int n  = (q0 >> 5) + 1;
  const int n0 = (n + 1) >> 1;
  const int ts = c ? n0 : 0;
  const int te = c ? n : n0;

  const char* kbase = (const char*)(kg + (size_t)b * 4096 * 768);
  const f16*  vbase = vt + (size_t)b * 768 * 4096;

  // ---- Q rows for this wave's QK^T tile -> registers (48 VGPR)
  f16x8 qreg[12];
  {
    const f16* qp = qg + ((size_t)b * 4096 + q0 + qi * 16 + fr) * 768 + dh * 384 + fq * 8;
#pragma unroll
    for (int kk = 0; kk < 12; ++kk) qreg[kk] = *(const f16x8*)(qp + kk * 32);
  }

  if (tid < 32) { mS[tid] = -1e30f; lS[tid] = 0.f; }

  f32x4 acc[2][6] = {};
  f16x8 vA[6], vB[6];

  auto stageK = [&](int t) {
    const char* kb = kbase + (size_t)(t * 32) * 1536;
    char* dst = smem + ((t & 1) ? SM_K1 : SM_K0);
#pragma unroll
    for (int i = 0; i < 6; ++i) {
      int lin = wv * 6144 + i * 1024 + lane * 16;
      int row = lin / 1536, cb = lin - row * 1536;
      gload_lds16(kb + (size_t)row * 1536 + (cb ^ ((row & 7) << 4)),
                  dst + wv * 6144 + i * 1024);
    }
  };

  auto loadV = [&](int t, f16x8 (&vr)[6]) {
    const f16* vp = vbase + (size_t)(wv * 96 + fr) * 4096 + t * 32 + fq * 8;
#pragma unroll
    for (int ct = 0; ct < 6; ++ct)
      vr[ct] = *(const f16x8*)(vp + (size_t)ct * 16 * 4096);
  };

  auto qkt = [&](int t) {   // QK^T(t) from K-LDS parity t -> S parity t
    const char* kb = smem + ((t & 1) ? SM_K1 : SM_K0);
    const int krow = ki * 16 + fr;
    const int kswz = (krow & 7) << 4;
    f32x4 sa = {}, sb = {};
#pragma unroll
    for (int kk = 0; kk < 12; kk += 2) {
      int by = krow * 1536 + dh * 768 + kk * 64 + fq * 16;
      f16x8 k0 = *(const f16x8*)(kb + (by ^ kswz));
      f16x8 k1 = *(const f16x8*)(kb + ((by + 64) ^ kswz));
      sa = __builtin_amdgcn_mfma_f32_16x16x32_f16(qreg[kk],     k0, sa, 0, 0, 0);
      sb = __builtin_amdgcn_mfma_f32_16x16x32_f16(qreg[kk + 1], k1, sb, 0, 0, 0);
    }
    sa = sa + sb;
    float* sdst = (float*)(smem + SM_SS + ((t & 1) ? 8192 : 0) + dh * 4096)
                  + (qi * 16 + fq * 4) * 32 + ki * 16 + fr;
#pragma unroll
    for (int r = 0; r < 4; ++r) sdst[r * 32] = sa[r];
  };

  auto softmax_f = [&](int t) {
    const int kv0 = t * 32;
    const float* S0 = (const float*)(smem + SM_SS + ((t & 1) ? 8192 : 0));
    const float* S1 = S0 + 1024;
    const int row = tid >> 4, sub = tid & 15;
    const int c0 = sub * 2;
    float a0 = S0[row * 32 + c0]     + S1[row * 32 + c0];
    float a1 = S0[row * 32 + c0 + 1] + S1[row * 32 + c0 + 1];
    const int grow = q0 + row;
    if (kv0 + c0     > grow) a0 = -1e30f;
    if (kv0 + c0 + 1 > grow) a1 = -1e30f;
    float mx = fmaxf(a0, a1);
    mx = fmaxf(mx, __shfl_xor(mx, 1));
    mx = fmaxf(mx, __shfl_xor(mx, 2));
    mx = fmaxf(mx, __shfl_xor(mx, 4));
    mx = fmaxf(mx, __shfl_xor(mx, 8));
    float mo = mS[row];
    float mn = fmaxf(mo, mx);
    float p0v = __expf(a0 - mn), p1v = __expf(a1 - mn);
    float sum = p0v + p1v;
    sum += __shfl_xor(sum, 1);
    sum += __shfl_xor(sum, 2);
    sum += __shfl_xor(sum, 4);
    sum += __shfl_xor(sum, 8);
    if (sub == 0) {
      float f = __expf(mo - mn);
      mS[row] = mn; fS[row] = f; lS[row] = lS[row] * f + sum;
    }
    f16x2 ph; ph[0] = (f16)p0v; ph[1] = (f16)p1v;
    int by = row * 64 + sub * 4;
    *(f16x2*)(Ps + (by ^ (((row >> 1) & 3) << 4))) = ph;
  };

  auto ITER = [&](int t, f16x8 (&vCon)[6], f16x8 (&vNxt)[6]) {
    const bool haveN1 = (t + 1 < te);
    const bool haveN2 = (t + 2 < te);
    // ---- region A
    asm volatile("s_waitcnt vmcnt(6)" ::: "memory");   // K[t+1] landed (keeps V(t))
    __builtin_amdgcn_s_barrier();
    if (haveN2) stageK(t + 2);
    asm volatile("" ::: "memory");                     // pin K-issue before V-issue
    if (haveN1) loadV(t + 1, vNxt);
    asm volatile("" ::: "memory");
    if (haveN1) qkt(t + 1);                            // MFMA stream
    softmax_f(t);                                      // latency chain (interleaved)
    asm volatile("s_waitcnt lgkmcnt(0)" ::: "memory");
    __builtin_amdgcn_s_barrier();
    // ---- region B
    {
      f32x4 f0 = *(const f32x4*)(fS + fq * 4);
      f32x4 f1 = *(const f32x4*)(fS + 16 + fq * 4);
      bool nd = (f0[0] < 1.f) || (f0[1] < 1.f) || (f0[2] < 1.f) || (f0[3] < 1.f) ||
                (f1[0] < 1.f) || (f1[1] < 1.f) || (f1[2] < 1.f) || (f1[3] < 1.f);
      if (__any(nd)) {
#pragma unroll
        for (int ct = 0; ct < 6; ++ct)
#pragma unroll
          for (int r = 0; r < 4; ++r) {
            acc[0][ct][r] *= f0[r];
            acc[1][ct][r] *= f1[r];
          }
      }
      int byA0 = (fr * 64 + fq * 16) ^ (((fr >> 1) & 3) << 4);
      int rb = 16 + fr;
      int byA1 = (rb * 64 + fq * 16) ^ (((rb >> 1) & 3) << 4);
      f16x8 pa0 = *(const f16x8*)(Ps + byA0);
      f16x8 pa1 = *(const f16x8*)(Ps + byA1);
      if (haveN2)      { asm volatile("s_waitcnt vmcnt(12)" ::: "memory"); }
      else if (haveN1) { asm volatile("s_waitcnt vmcnt(6)"  ::: "memory"); }
      else             { asm volatile("s_waitcnt vmcnt(0)"  ::: "memory"); }
      __builtin_amdgcn_s_setprio(1);
#pragma unroll
      for (int ct = 0; ct < 6; ++ct) {
        acc[0][ct] = __builtin_amdgcn_mfma_f32_16x16x32_f16(pa0, vCon[ct], acc[0][ct], 0, 0, 0);
        acc[1][ct] = __builtin_amdgcn_mfma_f32_16x16x32_f16(pa1, vCon[ct], acc[1][ct], 0, 0, 0);
      }
      __builtin_amdgcn_s_setprio(0);
    }
  };

  // ---- prologue
  if (ts < te) {
    stageK(ts);
    asm volatile("s_waitcnt vmcnt(0)" ::: "memory");
    __builtin_amdgcn_s_barrier();
    if (ts + 1 < te) stageK(ts + 1);
    asm volatile("" ::: "memory");
    loadV(ts, vA);
    asm volatile("" ::: "memory");
    qkt(ts);
    asm volatile("s_waitcnt lgkmcnt(0)" ::: "memory");
  }

  for (int t = ts; t < te; t += 2) {
    ITER(t, vA, vB);
    if (t + 1 < te) ITER(t + 1, vB, vA);
  }

  // ---- epilogue: unnormalized partial + (m,l)
  const size_t obase = (size_t)b * 4096 + q0;
  if (c == 0) {
#pragma unroll
    for (int ct = 0; ct < 6; ++ct) {
      int d = wv * 96 + ct * 16 + fr;
#pragma unroll
      for (int r = 0; r < 4; ++r) {
        p0[(obase + fq * 4 + r) * 768 + d]      = (f16)acc[0][ct][r];
        p0[(obase + 16 + fq * 4 + r) * 768 + d] = (f16)acc[1][ct][r];
      }
    }
  } else {
#pragma unroll
    for (int ct = 0; ct < 6; ++ct) {
      int d = wv * 96 + ct * 16 + fr;
#pragma unroll
      for (int r = 0; r < 4; ++r) {
        p1[(obase + fq * 4 + r) * 768 + d]      = acc[0][ct][r];
        p1[(obase + 16 + fq * 4 + r) * 768 + d] = acc[1][ct][r];
      }
    }
  }
  if (tid < 32) {
    float* mlp = ml + ((size_t)(c * 2 + b) * 4096 + q0 + tid) * 2;
    mlp[0] = mS[tid];
    mlp[1] = lS[tid];
  }
}

// ---------------------------------------------------------------- combine
__global__ __launch_bounds__(256) void attn_combine(
    const float* __restrict__ x, const f16* __restrict__ p0,
    const float* __restrict__ ml, float* __restrict__ out) {
  int i = blockIdx.x * 256 + threadIdx.x;
  int row = i / 192;
  int b = row >> 12, s = row & 4095;
  const float* m0p = ml + ((size_t)b * 4096 + s) * 2;
  const float* m1p = ml + ((size_t)(2 + b) * 4096 + s) * 2;
  float m0 = m0p[0], l0 = m0p[1];
  float m1 = m1p[0], l1 = m1p[1];
  float m  = fmaxf(m0, m1);
  float f0 = __expf(m0 - m), f1 = __expf(m1 - m);
  float inv = 1.f / (l0 * f0 + l1 * f1);
  f32x4 a1 = ((const f32x4*)out)[i];
  f16x4 a0 = ((const f16x4*)p0)[i];
  f32x4 xv = ((const f32x4*)x)[i];
  f32x4 o;
#pragma unroll
  for (int r = 0; r < 4; ++r)
    o[r] = xv[r] + ((float)a0[r] * f0 + a1[r] * f1) * inv;
  ((f32x4*)out)[i] = o;
}

// ---------------------------------------------------------------- launch
extern "C" void kernel_launch(void* const* d_in, const int* in_sizes, int n_in,
                              void* d_out, int out_size, void* d_ws, size_t ws_size,
                              hipStream_t stream) {
  const float* x  = (const float*)d_in[0];
  const float* Wp = (const float*)d_in[1];
  float* out = (float*)d_out;

  char* ws = (char*)d_ws;
  f16* x_h  = (f16*)(ws);                    // reused as p0 after proj
  f16* w_h  = (f16*)(ws + 12582912);         // reused as ml after proj
  f16* q_h  = (f16*)(ws + 16121856);
  f16* k_h  = (f16*)(ws + 28704768);
  f16* vt_h = (f16*)(ws + 41287680);

  f16*   p0 = x_h;
  float* ml = (float*)w_h;

  hipFuncSetAttribute(reinterpret_cast<const void*>(attn_part),
                      hipFuncAttributeMaxDynamicSharedMemorySize, SM_SZ);

  cvt_f32_f16<<<(M_TOK * D_MODEL) / 1024, 256, 0, stream>>>(x, x_h, (M_TOK * D_MODEL) / 4);
  cvt_f32_f16<<<(N3 * D_MODEL) / 1024, 256, 0, stream>>>(Wp, w_h, (N3 * D_MODEL) / 4);
  proj_gemm<<<dim3(64, 18), 256, 0, stream>>>(x_h, w_h, q_h, k_h, vt_h);
  attn_part<<<512, 512, SM_SZ, stream>>>(q_h, k_h, vt_h, p0, out, ml);
  attn_combine<<<(M_TOK * D_MODEL) / 1024, 256, 0, stream>>>(x, p0, ml, out);
}

// Round 5
// 284.182 us; speedup vs baseline: 1.2539x; 1.2539x over previous
//
#include <hip/hip_runtime.h>
#include <hip/hip_bf16.h>
#include <hip/hip_fp16.h>

typedef _Float16 f16;
typedef _Float16 f16x8 __attribute__((ext_vector_type(8)));
typedef _Float16 f16x4 __attribute__((ext_vector_type(4)));
typedef _Float16 f16x2 __attribute__((ext_vector_type(2)));
typedef float f32x4 __attribute__((ext_vector_type(4)));

#define D_MODEL 768
#define S_CTX   4096
#define NBATCH  2
#define M_TOK   (NBATCH * S_CTX)   // 8192
#define N3      (3 * D_MODEL)      // 2304

// ---------------------------------------------------------------- utilities
__device__ __forceinline__ void gload_lds16(const void* g, void* l) {
  __builtin_amdgcn_global_load_lds(
      (__attribute__((address_space(1))) unsigned int*)g,
      (__attribute__((address_space(3))) unsigned int*)l, 16, 0, 0);
}

// ---------------------------------------------------------------- fp32->fp16
__global__ __launch_bounds__(256) void cvt_f32_f16(const float* __restrict__ s,
                                                   f16* __restrict__ d, int n4) {
  int i = blockIdx.x * 256 + threadIdx.x;
  if (i >= n4) return;
  f32x4 v = ((const f32x4*)s)[i];
  f16x4 h;
  h[0] = (f16)v[0]; h[1] = (f16)v[1]; h[2] = (f16)v[2]; h[3] = (f16)v[3];
  ((f16x4*)d)[i] = h;
}

// ---------------------------------------------------------------- projection
__global__ __launch_bounds__(256, 2) void proj_gemm(
    const f16* __restrict__ A, const f16* __restrict__ B,
    f16* __restrict__ qh, f16* __restrict__ kh, f16* __restrict__ vth) {
  __shared__ f16 As[128 * 32];
  __shared__ f16 Bs[128 * 32];

  const int tid  = threadIdx.x;
  const int w    = tid >> 6, lane = tid & 63;
  const int wr   = w >> 1,   wc   = w & 1;
  const int bm0  = blockIdx.x * 128, bn0 = blockIdx.y * 128;
  const int srow = lane >> 2;
  const int scol = (lane & 3) * 8;

  f32x4 acc[4][4] = {};

  const f16* gA = A + (size_t)bm0 * 768;
  const f16* gB = B + (size_t)bn0 * 768;

  for (int kt = 0; kt < 24; ++kt) {
    __syncthreads();
    const int k0 = kt * 32 + scol;
#pragma unroll
    for (int cc = 0; cc < 2; ++cc) {
      int c = w + cc * 4;
      gload_lds16(gA + (size_t)(c * 16 + srow) * 768 + k0, (char*)As + c * 1024);
      gload_lds16(gB + (size_t)(c * 16 + srow) * 768 + k0, (char*)Bs + c * 1024);
    }
    __syncthreads();

    const int fr = lane & 15, fk = (lane >> 4) * 8;
    f16x8 af[4], bf[4];
#pragma unroll
    for (int i = 0; i < 4; ++i)
      af[i] = *(const f16x8*)(As + (wr * 64 + i * 16 + fr) * 32 + fk);
#pragma unroll
    for (int j = 0; j < 4; ++j)
      bf[j] = *(const f16x8*)(Bs + (wc * 64 + j * 16 + fr) * 32 + fk);
#pragma unroll
    for (int i = 0; i < 4; ++i)
#pragma unroll
      for (int j = 0; j < 4; ++j)
        acc[i][j] = __builtin_amdgcn_mfma_f32_16x16x32_f16(af[i], bf[j], acc[i][j], 0, 0, 0);
  }

  const int fr = lane & 15, fq = lane >> 4;
#pragma unroll
  for (int i = 0; i < 4; ++i) {
#pragma unroll
    for (int j = 0; j < 4; ++j) {
      int gn      = bn0 + wc * 64 + j * 16 + fr;
      int gm_base = bm0 + wr * 64 + i * 16 + fq * 4;
      if (gn < 1536) {
        f16* dst = (gn < 768) ? qh : kh;
        int  col = (gn < 768) ? gn : gn - 768;
#pragma unroll
        for (int r = 0; r < 4; ++r)
          dst[(size_t)(gm_base + r) * 768 + col] = (f16)acc[i][j][r];
      } else {
        int d = gn - 1536;
        int bb = gm_base >> 12, s = gm_base & 4095;
        f16x4 h;
        h[0] = (f16)acc[i][j][0]; h[1] = (f16)acc[i][j][1];
        h[2] = (f16)acc[i][j][2]; h[3] = (f16)acc[i][j][3];
        *(f16x4*)(vth + ((size_t)bb * 768 + d) * 4096 + s) = h;
      }
    }
  }
}

// ---------------------------------------------------------------- attention
// R3 skeleton (3 barriers/step, K LDS-double-buffered via global_load_lds)
// with ONE change: V goes straight to registers (6 f16x8/wave), never LDS.
// Step top issues V(t)->regs first, then K[t+1]->LDS; PV's V-wait is the
// compiler's data-dependency vmcnt(6) (K stays in flight); end-of-step
// vmcnt(0) drains K only.
#define SM_K0   0
#define SM_K1   49152
#define SM_SS   98304    // float [2 dh][32][32]
#define SM_PS   106496   // f16 [32][64B] swizzled
#define SM_M    108544
#define SM_L    108672
#define SM_F    108800
#define SM_SZ   108928

__global__ __launch_bounds__(512, 2) void attn_part(
    const f16* __restrict__ qg, const f16* __restrict__ kg,
    const f16* __restrict__ vt, f16* __restrict__ p0,
    float* __restrict__ p1, float* __restrict__ ml) {
  extern __shared__ __align__(16) char smem[];
  char*  Kb0 = smem + SM_K0;
  char*  Kb1 = smem + SM_K1;
  float* Ss0 = (float*)(smem + SM_SS);
  float* Ss1 = Ss0 + 1024;
  char*  Ps  = smem + SM_PS;
  float* mS  = (float*)(smem + SM_M);
  float* lS  = (float*)(smem + SM_L);
  float* fS  = (float*)(smem + SM_F);

  const int tid  = threadIdx.x;
  const int wv   = tid >> 6, lane = tid & 63;
  const int fr   = lane & 15, fq = lane >> 4;
  const int qi   = wv >> 2, ki = (wv >> 1) & 1, dh = wv & 1;

  // pairing schedule: round 1 qb 127..64 desc, round 2 qb 63..0 desc
  const int u = blockIdx.x;
  int vv = (u < 256) ? u : (u - 256);
  const int qb = ((u < 256) ? 127 : 63) - (vv >> 2);
  const int b  = (vv >> 1) & 1;
  const int c  = vv & 1;
  const int q0 = qb * 32;
  const int n  = (q0 >> 5) + 1;       // KV steps of 32 for this q-block
  const int n0 = (n + 1) >> 1;
  const int ts = c ? n0 : 0;
  const int te = c ? n : n0;

  const char* kbase = (const char*)(kg + (size_t)b * 4096 * 768);
  const f16*  vbase = vt + (size_t)b * 768 * 4096;
  const f16*  vp0   = vbase + (size_t)(wv * 96 + fr) * 4096 + fq * 8;

  // ---- Q rows for this wave's QK^T tile -> registers (48 VGPR)
  f16x8 qreg[12];
  {
    const f16* qp = qg + ((size_t)b * 4096 + q0 + qi * 16 + fr) * 768 + dh * 384 + fq * 8;
#pragma unroll
    for (int kk = 0; kk < 12; ++kk) qreg[kk] = *(const f16x8*)(qp + kk * 32);
  }

  if (tid < 32) { mS[tid] = -1e30f; lS[tid] = 0.f; }

  f32x4 acc[2][6] = {};

  // ---- prologue: stage K[ts]
  if (ts < te) {
    const char* kb = kbase + (size_t)(ts * 32) * 1536;
    char* dst = (ts & 1) ? Kb1 : Kb0;
#pragma unroll
    for (int i = 0; i < 6; ++i) {
      int lin = wv * 6144 + i * 1024 + lane * 16;
      int row = lin / 1536, cb = lin - row * 1536;
      gload_lds16(kb + (size_t)row * 1536 + (cb ^ ((row & 7) << 4)),
                  dst + wv * 6144 + i * 1024);
    }
  }
  asm volatile("s_waitcnt vmcnt(0)" ::: "memory");
  __builtin_amdgcn_s_barrier();

  for (int t = ts; t < te; ++t) {
    const int kv0 = t * 32;
    const bool pf = (t + 1 < te);

    // ---- V(t) -> registers (issued first, so PV waits at vmcnt(6))
    f16x8 vreg[6];
    {
      const f16* vp = vp0 + kv0;
#pragma unroll
      for (int ct = 0; ct < 6; ++ct)
        vreg[ct] = *(const f16x8*)(vp + (size_t)ct * 16 * 4096);
    }
    // ---- issue K[t+1] -> LDS (stays in flight across the whole step)
    if (pf) {
      const char* kb = kbase + (size_t)(kv0 + 32) * 1536;
      char* dst = ((t + 1) & 1) ? Kb1 : Kb0;
#pragma unroll
      for (int i = 0; i < 6; ++i) {
        int lin = wv * 6144 + i * 1024 + lane * 16;
        int row = lin / 1536, cb = lin - row * 1536;
        gload_lds16(kb + (size_t)row * 1536 + (cb ^ ((row & 7) << 4)),
                    dst + wv * 6144 + i * 1024);
      }
    }

    // ---- QK^T: 12 MFMA over this wave's D-half
    {
      const char* kbuf = (t & 1) ? Kb1 : Kb0;
      f32x4 sc = {};
      const int krow = ki * 16 + fr;
      const int kswz = (krow & 7) << 4;
      __builtin_amdgcn_s_setprio(1);
#pragma unroll
      for (int kk = 0; kk < 12; ++kk) {
        int by = krow * 1536 + dh * 768 + kk * 64 + fq * 16;
        f16x8 kf = *(const f16x8*)(kbuf + (by ^ kswz));
        sc = __builtin_amdgcn_mfma_f32_16x16x32_f16(qreg[kk], kf, sc, 0, 0, 0);
      }
      __builtin_amdgcn_s_setprio(0);
      float* sdst = (dh ? Ss1 : Ss0) + (qi * 16 + fq * 4) * 32 + ki * 16 + fr;
#pragma unroll
      for (int r = 0; r < 4; ++r) sdst[r * 32] = sc[r];
    }
    asm volatile("s_waitcnt lgkmcnt(0)" ::: "memory");
    __builtin_amdgcn_s_barrier();                       // (1) S complete

    // ---- online softmax: row = tid>>4, 2 cols per thread
    {
      const int row = tid >> 4, sub = tid & 15;
      const int c0 = sub * 2;
      float a0 = Ss0[row * 32 + c0]     + Ss1[row * 32 + c0];
      float a1 = Ss0[row * 32 + c0 + 1] + Ss1[row * 32 + c0 + 1];
      const int grow = q0 + row;
      if (kv0 + c0     > grow) a0 = -1e30f;
      if (kv0 + c0 + 1 > grow) a1 = -1e30f;
      float mx = fmaxf(a0, a1);
      mx = fmaxf(mx, __shfl_xor(mx, 1));
      mx = fmaxf(mx, __shfl_xor(mx, 2));
      mx = fmaxf(mx, __shfl_xor(mx, 4));
      mx = fmaxf(mx, __shfl_xor(mx, 8));
      float mo = mS[row];
      float mn = fmaxf(mo, mx);
      float p0v = __expf(a0 - mn), p1v = __expf(a1 - mn);
      float sum = p0v + p1v;
      sum += __shfl_xor(sum, 1);
      sum += __shfl_xor(sum, 2);
      sum += __shfl_xor(sum, 4);
      sum += __shfl_xor(sum, 8);
      if (sub == 0) {
        float f = __expf(mo - mn);
        mS[row] = mn; fS[row] = f; lS[row] = lS[row] * f + sum;
      }
      f16x2 ph; ph[0] = (f16)p0v; ph[1] = (f16)p1v;
      int by = row * 64 + sub * 4;
      *(f16x2*)(Ps + (by ^ (((row >> 1) & 3) << 4))) = ph;
    }
    asm volatile("s_waitcnt lgkmcnt(0)" ::: "memory");
    __builtin_amdgcn_s_barrier();                       // (2) P, m/l/f complete

    // ---- rescale + PV (V is a VGPR data dependency; K[t+1] stays in flight)
    {
      f32x4 f0 = *(const f32x4*)(fS + fq * 4);
      f32x4 f1 = *(const f32x4*)(fS + 16 + fq * 4);
#pragma unroll
      for (int ct = 0; ct < 6; ++ct)
#pragma unroll
        for (int r = 0; r < 4; ++r) {
          acc[0][ct][r] *= f0[r];
          acc[1][ct][r] *= f1[r];
        }
      int byA0 = (fr * 64 + fq * 16) ^ (((fr >> 1) & 3) << 4);
      int rb = 16 + fr;
      int byA1 = (rb * 64 + fq * 16) ^ (((rb >> 1) & 3) << 4);
      f16x8 pa0 = *(const f16x8*)(Ps + byA0);
      f16x8 pa1 = *(const f16x8*)(Ps + byA1);
      __builtin_amdgcn_s_setprio(1);
#pragma unroll
      for (int ct = 0; ct < 6; ++ct) {
        acc[0][ct] = __builtin_amdgcn_mfma_f32_16x16x32_f16(pa0, vreg[ct], acc[0][ct], 0, 0, 0);
        acc[1][ct] = __builtin_amdgcn_mfma_f32_16x16x32_f16(pa1, vreg[ct], acc[1][ct], 0, 0, 0);
      }
      __builtin_amdgcn_s_setprio(0);
    }
    asm volatile("s_waitcnt vmcnt(0) lgkmcnt(0)" ::: "memory");
    __builtin_amdgcn_s_barrier();                       // (3) K[t+1] landed
  }

  // ---- epilogue: unnormalized partial + (m,l)
  const size_t obase = (size_t)b * 4096 + q0;
  if (c == 0) {
#pragma unroll
    for (int ct = 0; ct < 6; ++ct) {
      int d = wv * 96 + ct * 16 + fr;
#pragma unroll
      for (int r = 0; r < 4; ++r) {
        p0[(obase + fq * 4 + r) * 768 + d]      = (f16)acc[0][ct][r];
        p0[(obase + 16 + fq * 4 + r) * 768 + d] = (f16)acc[1][ct][r];
      }
    }
  } else {
#pragma unroll
    for (int ct = 0; ct < 6; ++ct) {
      int d = wv * 96 + ct * 16 + fr;
#pragma unroll
      for (int r = 0; r < 4; ++r) {
        p1[(obase + fq * 4 + r) * 768 + d]      = acc[0][ct][r];
        p1[(obase + 16 + fq * 4 + r) * 768 + d] = acc[1][ct][r];
      }
    }
  }
  if (tid < 32) {
    float* mlp = ml + ((size_t)(c * 2 + b) * 4096 + q0 + tid) * 2;
    mlp[0] = mS[tid];
    mlp[1] = lS[tid];
  }
}

// ---------------------------------------------------------------- combine
__global__ __launch_bounds__(256) void attn_combine(
    const float* __restrict__ x, const f16* __restrict__ p0,
    const float* __restrict__ ml, float* __restrict__ out) {
  int i = blockIdx.x * 256 + threadIdx.x;
  int row = i / 192;
  int b = row >> 12, s = row & 4095;
  const float* m0p = ml + ((size_t)b * 4096 + s) * 2;
  const float* m1p = ml + ((size_t)(2 + b) * 4096 + s) * 2;
  float m0 = m0p[0], l0 = m0p[1];
  float m1 = m1p[0], l1 = m1p[1];
  float m  = fmaxf(m0, m1);
  float f0 = __expf(m0 - m), f1 = __expf(m1 - m);
  float inv = 1.f / (l0 * f0 + l1 * f1);
  f32x4 a1 = ((const f32x4*)out)[i];
  f16x4 a0 = ((const f16x4*)p0)[i];
  f32x4 xv = ((const f32x4*)x)[i];
  f32x4 o;
#pragma unroll
  for (int r = 0; r < 4; ++r)
    o[r] = xv[r] + ((float)a0[r] * f0 + a1[r] * f1) * inv;
  ((f32x4*)out)[i] = o;
}

// ---------------------------------------------------------------- launch
extern "C" void kernel_launch(void* const* d_in, const int* in_sizes, int n_in,
                              void* d_out, int out_size, void* d_ws, size_t ws_size,
                              hipStream_t stream) {
  const float* x  = (const float*)d_in[0];
  const float* Wp = (const float*)d_in[1];
  float* out = (float*)d_out;

  char* ws = (char*)d_ws;
  f16* x_h  = (f16*)(ws);                    // reused as p0 after proj
  f16* w_h  = (f16*)(ws + 12582912);         // reused as ml after proj
  f16* q_h  = (f16*)(ws + 16121856);
  f16* k_h  = (f16*)(ws + 28704768);
  f16* vt_h = (f16*)(ws + 41287680);

  f16*   p0 = x_h;
  float* ml = (float*)w_h;

  hipFuncSetAttribute(reinterpret_cast<const void*>(attn_part),
                      hipFuncAttributeMaxDynamicSharedMemorySize, SM_SZ);

  cvt_f32_f16<<<(M_TOK * D_MODEL) / 1024, 256, 0, stream>>>(x, x_h, (M_TOK * D_MODEL) / 4);
  cvt_f32_f16<<<(N3 * D_MODEL) / 1024, 256, 0, stream>>>(Wp, w_h, (N3 * D_MODEL) / 4);
  proj_gemm<<<dim3(64, 18), 256, 0, stream>>>(x_h, w_h, q_h, k_h, vt_h);
  attn_part<<<512, 512, SM_SZ, stream>>>(q_h, k_h, vt_h, p0, out, ml);
  attn_combine<<<(M_TOK * D_MODEL) / 1024, 256, 0, stream>>>(x, p0, ml, out);
}